// Round 20
// baseline (109.408 us; speedup 1.0000x reference)
//
#include <hip/hip_runtime.h>

typedef __bf16 bf16_t;
typedef __attribute__((ext_vector_type(2))) __bf16 bf16x2;
typedef __attribute__((ext_vector_type(4))) __bf16 bf16x4;
typedef __attribute__((ext_vector_type(8))) __bf16 bf16x8;
typedef __attribute__((ext_vector_type(4))) float f32x4;
typedef __attribute__((ext_vector_type(16))) float f32x16;

#define MFMA16(a, b, c) __builtin_amdgcn_mfma_f32_16x16x32_bf16((a), (b), (c), 0, 0, 0)
#define MFMA32(a, b, c) __builtin_amdgcn_mfma_f32_32x32x16_bf16((a), (b), (c), 0, 0, 0)
#define AS1 __attribute__((address_space(1)))
#define AS3 __attribute__((address_space(3)))

// Problem: B=8 S=1024 D=768 H=16 Dh=64 OD=1024, M = B*S = 8192
static constexpr unsigned XB_OFF = 0u;                          // x bf16 row-major: 12,582,912
static constexpr unsigned WT_OFF = 12582912u;                   // wT bf16 (3,1024,768): 4,718,592
static constexpr unsigned Q_OFF  = WT_OFF + 4718592u;           // Qf bf16: 16,777,216
static constexpr unsigned K_OFF  = Q_OFF + 16777216u;
static constexpr unsigned VT_OFF = K_OFF + 16777216u;           // end = 67,633,152

// ---------------- merged cast kernel (unchanged) ----------------
__global__ __launch_bounds__(256) void cast_kernel(const float4* __restrict__ x4,
                                                   bf16x4* __restrict__ out4,
                                                   const float* __restrict__ qw,
                                                   const float* __restrict__ kw,
                                                   const float* __restrict__ vw,
                                                   bf16_t* __restrict__ wT) {
    if (blockIdx.x < 6144u) {
        unsigned i = blockIdx.x * 256u + threadIdx.x;
        float4 v = x4[i];
        bf16x4 o;
        o[0] = (bf16_t)v.x; o[1] = (bf16_t)v.y; o[2] = (bf16_t)v.z; o[3] = (bf16_t)v.w;
        out4[i] = o;
    } else {
        unsigned t = (blockIdx.x - 6144u) * 256u + threadIdx.x;
        unsigned w  = t / 196608u;
        unsigned r  = t % 196608u;
        unsigned n  = r % 1024u;
        unsigned k4 = r / 1024u;
        const float* src = (w == 0u) ? qw : (w == 1u) ? kw : vw;
        float s = (w == 0u) ? 0.18033688011112043f : 1.0f;   // 0.125*log2(e) folded for exp2
        bf16x4 o;
#pragma unroll
        for (int i = 0; i < 4; ++i) o[i] = (bf16_t)(src[(k4 * 4u + i) * 1024u + n] * s);
        *(bf16x4*)&wT[(w * 1024u + n) * 768u + k4 * 4u] = o;
    }
}

// ---------------- fused QKV projection GEMM (r19, ≈r18 perf) -----------------
__global__ __launch_bounds__(256, 2) void proj_kernel(const bf16_t* __restrict__ xb,
                                                      const bf16_t* __restrict__ wT,
                                                      bf16_t* __restrict__ q,
                                                      bf16_t* __restrict__ k,
                                                      bf16_t* __restrict__ vt) {
    __shared__ __align__(16) char smem[73728];          // 72KB: As 48KB | Bs 24KB
    bf16_t* Asp = (bf16_t*)smem;                        // 3 slots x 8192 elems
    bf16_t* Bsp = (bf16_t*)(smem + 49152);              // 3 slots x 4096 elems
    const int id = blockIdx.x;
    const int work = (id & 7) * 96 + (id >> 3);         // bijective, 768 = 8*96
    const int nb = work & 7, mb = (work >> 3) & 31, wsel = work >> 8;
    const int t = threadIdx.x;
    const int w = t >> 6, l = t & 63;
    const int lo = l & 15, hi = l >> 4;
    const int wm = w >> 1, wn = w & 1;                  // 2x2 waves; per-wave 128x64
    const bf16_t* abase = xb + mb * 256 * 768;
    const bf16_t* bbase = wT + wsel * (1024 * 768) + nb * 128 * 768;
    const int srow = w * 16 + (l >> 2);
    const int gsrc = ((l & 3) ^ ((l >> 3) & 3)) * 8;
    const int rg = (hi ^ ((lo >> 1) & 3)) << 3;         // read-side granule

#define STAGE(slot, p)                                                              \
    do {                                                                            \
        const int ko_ = (p) * 32 + gsrc;                                            \
        _Pragma("unroll")                                                           \
        for (int g_ = 0; g_ < 4; ++g_)                                              \
            __builtin_amdgcn_global_load_lds(                                       \
                (const AS1 void*)(abase + (g_ * 64 + srow) * 768 + ko_),            \
                (AS3 void*)(Asp + (slot) * 8192 + g_ * 2048 + w * 512), 16, 0, 0);  \
        _Pragma("unroll")                                                           \
        for (int g_ = 0; g_ < 2; ++g_)                                              \
            __builtin_amdgcn_global_load_lds(                                       \
                (const AS1 void*)(bbase + (g_ * 64 + srow) * 768 + ko_),            \
                (AS3 void*)(Bsp + (slot) * 4096 + g_ * 2048 + w * 512), 16, 0, 0);  \
    } while (0)

    bf16x8 af[8], bfr[4];
#define DSREAD(slotv)                                                             \
    do {                                                                          \
        const bf16_t* Ab_ = Asp + (slotv) * 8192;                                 \
        const bf16_t* Bb_ = Bsp + (slotv) * 4096;                                 \
        _Pragma("unroll") for (int m_ = 0; m_ < 8; ++m_)                          \
            af[m_] = *(const bf16x8*)&Ab_[(wm * 128 + m_ * 16 + lo) * 32 + rg];   \
        _Pragma("unroll") for (int n_ = 0; n_ < 4; ++n_)                          \
            bfr[n_] = *(const bf16x8*)&Bb_[(wn * 64 + n_ * 16 + lo) * 32 + rg];   \
    } while (0)

#define DOMFMA()                                                                  \
    do {                                                                          \
        __builtin_amdgcn_s_setprio(1);                                            \
        _Pragma("unroll") for (int m_ = 0; m_ < 8; ++m_)                          \
        _Pragma("unroll") for (int n_ = 0; n_ < 4; ++n_)                          \
            acc[m_][n_] = MFMA16(af[m_], bfr[n_], acc[m_][n_]);                   \
        __builtin_amdgcn_s_setprio(0);                                            \
    } while (0)

    f32x4 acc[8][4];
#pragma unroll
    for (int m = 0; m < 8; ++m)
#pragma unroll
        for (int n = 0; n < 4; ++n)
#pragma unroll
            for (int i = 0; i < 4; ++i) acc[m][n][i] = 0.f;

    STAGE(0, 0);
    STAGE(1, 1);
    asm volatile("s_waitcnt vmcnt(6)" ::: "memory");
    __builtin_amdgcn_s_barrier();

    int slot = 0;
    for (int p = 0; p < 22; ++p) {
        DSREAD(slot);                                      // slot p published
        const int s2 = (slot + 2 >= 3) ? slot - 1 : slot + 2;
        STAGE(s2, p + 2);                                  // slot p-1: reads consumed at p-1
        DOMFMA();                                          // consumes DSREAD(p)
        asm volatile("s_waitcnt vmcnt(6)" ::: "memory");   // stage(p+1) landed
        __builtin_amdgcn_s_barrier();                      // publish slot p+1
        slot = (slot + 1 >= 3) ? 0 : slot + 1;
    }
    // tail: p = 22, 23
    DSREAD(1);
    DOMFMA();
    asm volatile("s_waitcnt vmcnt(0)" ::: "memory");       // stage(23) landed
    __builtin_amdgcn_s_barrier();
    DSREAD(2);
    DOMFMA();
#undef STAGE
#undef DSREAD
#undef DOMFMA

    // ---- epilogue: LDS transpose -> 16 coalesced 1KB chunk stores per wave ----
    asm volatile("s_waitcnt lgkmcnt(0)" ::: "memory");
    __builtin_amdgcn_s_barrier();            // all waves past final DSREAD; LDS free
    bf16_t* ep = (bf16_t*)(smem + (unsigned)w * 16384u);   // per-wave 16KB carve
    if (wsel != 2) {
        const int lA = ((lo >> 3) & 1) * 32 + hi * 4;
#pragma unroll
        for (int m = 0; m < 8; ++m)
#pragma unroll
            for (int n = 0; n < 4; ++n)
#pragma unroll
                for (int r = 0; r < 4; ++r)
                    ep[((m >> 1) * 4 + n) * 512 + (lA + (m & 1) * 16 + r) * 8 + (lo & 7)] =
                        (bf16_t)acc[m][n][r];
    } else {
#pragma unroll
        for (int m = 0; m < 8; ++m)
#pragma unroll
            for (int n = 0; n < 4; ++n)
#pragma unroll
                for (int r = 0; r < 4; ++r) {
                    const int sr = hi * 4 + r;   // ss&15
                    ep[((m >> 2) * 8 + (m & 3) * 2 + (n >> 1)) * 512
                       + (((sr >> 3) & 1) * 32 + (n & 1) * 16 + lo) * 8 + (sr & 7)] =
                        (bf16_t)acc[m][n][r];
                }
    }
    asm volatile("s_waitcnt lgkmcnt(0)" ::: "memory");
    __builtin_amdgcn_sched_barrier(0);       // rule #18: pin reads after the wait
    const unsigned headoff = (unsigned)((mb >> 2) * 16 + nb * 2 + wn) << 16;
    bf16_t* dst = (wsel == 0) ? q : (wsel == 1) ? k : vt;
#pragma unroll
    for (int c = 0; c < 16; ++c) {
        unsigned gchunk;
        if (wsel == 0) {
            const int m2 = c >> 2, sq = c & 3;
            gchunk = (unsigned)(((mb & 3) * 8 + wm * 4 + m2) * 4 + sq);
        } else if (wsel == 1) {
            const int m2 = c >> 2, sq = c & 3;
            gchunk = (unsigned)(((mb & 3) * 4 + wm * 2 + (m2 >> 1)) * 8 + sq * 2 + (m2 & 1));
        } else {
            const int ktl = c >> 3, S = (c >> 1) & 3, hl = c & 1;
            gchunk = (unsigned)(((mb & 3) * 4 + wm * 2 + ktl) * 8 + S * 2 + hl);
        }
        *(bf16x8*)&dst[headoff + gchunk * 512u + l * 8] = *(const bf16x8*)&ep[c * 512 + l * 8];
    }
}

// ---------------- flash attention: BARRIER-FREE direct-L2, 2-tile ILP --------
// r18's inner loop (2-tile ILP phase order + deferred lsum + permlane P^T +
// static-max softmax) on the r6 barrier-free skeleton: K/V fragments read
// directly from global (fragment-order -> coalesced 1KB wave reads; 8 waves
// per block on the SAME head -> 7/8 of reads are L1 hits; head pinned to one
// XCD's L2). ZERO barriers / waitcnt in the main loop -- waves self-schedule,
// ~4 waves/SIMD hide L1/L2 latency. LDS only for the wave-private epilogue
// transpose (64KB -> 2 blocks/CU).
__global__ __launch_bounds__(512) void attn_kernel(const bf16_t* __restrict__ Q,
                                                   const bf16_t* __restrict__ K,
                                                   const bf16_t* __restrict__ Vt,
                                                   float* __restrict__ out) {
    __shared__ __align__(16) char asmem[65536];    // epilogue olds only (8KB/wave)
    const int w = threadIdx.x >> 6, l = threadIdx.x & 63;   // w: 0..7
    const int hb = blockIdx.x & 127;             // head: fixes XCD by hb%8
    const int qblk = blockIdx.x >> 7;            // 0..3
    const int qw = qblk * 8 + w;                 // q-tile 0..31 within head
    const int b = hb >> 4, h = hb & 15;
    const int ln = l & 31, hi = l >> 5;
    const unsigned bh = (unsigned)hb << 16;
    const bf16_t* Qh = Q + bh;
    const bf16_t* Kh = K + bh;
    const bf16_t* Vh = Vt + bh;
    const int l8 = l * 8;

    bf16x8 qf[4];
#pragma unroll
    for (int s = 0; s < 4; ++s)
        qf[s] = *(const bf16x8*)&Qh[(qw * 4 + s) * 512 + l8];

    f32x16 of0, of1;
#pragma unroll
    for (int r = 0; r < 16; ++r) { of0[r] = 0.f; of1[r] = 0.f; }
    float sacc[16];
#pragma unroll
    for (int r = 0; r < 16; ++r) sacc[r] = 0.f;

#define ATILE_QK(Kt, sc0, sc1)                                                   \
    do {                                                                         \
        _Pragma("unroll") for (int r = 0; r < 16; ++r) { sc0[r] = 0.f; sc1[r] = 0.f; } \
        __builtin_amdgcn_s_setprio(1);                                           \
        _Pragma("unroll") for (int s = 0; s < 4; ++s) {                          \
            bf16x8 k0 = *(const bf16x8*)&(Kt)[(s * 2 + 0) * 512 + l8];           \
            bf16x8 k1 = *(const bf16x8*)&(Kt)[(s * 2 + 1) * 512 + l8];           \
            sc0 = MFMA32(k0, qf[s], sc0);                                        \
            sc1 = MFMA32(k1, qf[s], sc1);                                        \
        }                                                                        \
        __builtin_amdgcn_s_setprio(0);                                           \
    } while (0)

#define ATILE_SM(sc0, sc1, own)                                                  \
    do {                                                                         \
        float p0[16], p1[16];                                                    \
        _Pragma("unroll") for (int r = 0; r < 16; ++r) {                         \
            p0[r] = __builtin_amdgcn_exp2f(sc0[r]);                              \
            p1[r] = __builtin_amdgcn_exp2f(sc1[r]);                              \
        }                                                                        \
        _Pragma("unroll") for (int r = 0; r < 16; ++r) sacc[r] += p0[r] + p1[r]; \
        _Pragma("unroll") for (int t2 = 0; t2 < 8; ++t2) {                       \
            bf16x2 v0; v0[0] = (bf16_t)p0[2 * t2]; v0[1] = (bf16_t)p0[2 * t2 + 1]; \
            bf16x2 v1; v1[0] = (bf16_t)p1[2 * t2]; v1[1] = (bf16_t)p1[2 * t2 + 1]; \
            own[t2]     = __builtin_bit_cast(unsigned, v0);                      \
            own[8 + t2] = __builtin_bit_cast(unsigned, v1);                      \
        }                                                                        \
    } while (0)

#define ATILE_PV(Vtt, own)                                                       \
    do {                                                                         \
        bf16x8 vf0[4], vf1[4];                                                   \
        _Pragma("unroll") for (int S = 0; S < 4; ++S) {                          \
            vf0[S] = *(const bf16x8*)&(Vtt)[(S * 2 + 0) * 512 + l8];             \
            vf1[S] = *(const bf16x8*)&(Vtt)[(S * 2 + 1) * 512 + l8];             \
        }                                                                        \
        __builtin_amdgcn_s_setprio(1);                                           \
        _Pragma("unroll") for (int S = 0; S < 4; ++S) {                          \
            const int b0 = (S >> 1) * 8 + (S & 1) * 4;                           \
            unsigned w0 = own[b0 + 0], w2 = own[b0 + 2];                         \
            unsigned w1 = own[b0 + 1], w3 = own[b0 + 3];                         \
            asm("v_permlane32_swap_b32 %0, %1" : "+v"(w0), "+v"(w2));            \
            asm("v_permlane32_swap_b32 %0, %1" : "+v"(w1), "+v"(w3));            \
            union { unsigned u[4]; bf16x8 v; } pb;                               \
            pb.u[0] = w0; pb.u[1] = w1; pb.u[2] = w2; pb.u[3] = w3;              \
            of0 = MFMA32(vf0[S], pb.v, of0);                                     \
            of1 = MFMA32(vf1[S], pb.v, of1);                                     \
        }                                                                        \
        __builtin_amdgcn_s_setprio(0);                                           \
    } while (0)

    // main loop: 8 pairs, no barriers, no waitcnt -- compiler/HW self-schedule
    for (int p = 0; p < 8; ++p) {
        const bf16_t* KtA = Kh + (p * 2 + 0) * 4096;
        const bf16_t* VtA = Vh + (p * 2 + 0) * 4096;
        const bf16_t* KtB = Kh + (p * 2 + 1) * 4096;
        const bf16_t* VtB = Vh + (p * 2 + 1) * 4096;
        f32x16 scA0, scA1;
        ATILE_QK(KtA, scA0, scA1);
        unsigned ownA[16];
        ATILE_SM(scA0, scA1, ownA);
        f32x16 scB0, scB1;
        ATILE_QK(KtB, scB0, scB1);
        ATILE_PV(VtA, ownA);
        unsigned ownB[16];
        ATILE_SM(scB0, scB1, ownB);
        ATILE_PV(VtB, ownB);
    }
#undef ATILE_QK
#undef ATILE_SM
#undef ATILE_PV

    // epilogue: deferred lsum tree + normalize + XOR-swizzled transpose + store
#pragma unroll
    for (int st = 8; st >= 1; st >>= 1)
#pragma unroll
        for (int r = 0; r < 8; ++r)
            if (r < st) sacc[r] += sacc[r + st];
    float ltot = sacc[0] + __shfl_xor(sacc[0], 32);
    float inv = 1.f / ltot;
    float* ol = (float*)asmem + (unsigned)w * 2048u;   // per-wave 8KB carve
#pragma unroll
    for (int r = 0; r < 16; ++r) {
        int d = (r & 3) + 8 * (r >> 2) + 4 * hi;
        int d2 = 32 + d;
        ol[d * 32 + (ln ^ (d & 31))]    = of0[r] * inv;
        ol[d2 * 32 + (ln ^ (d2 & 31))]  = of1[r] * inv;
    }
    const unsigned obase = (unsigned)(b * 1024 + qw * 32) * 1024u + h * 64 + l;
#pragma unroll 8
    for (int qq = 0; qq < 32; ++qq)
        out[obase + qq * 1024u] = ol[l * 32 + (qq ^ (l & 31))];
}

extern "C" void kernel_launch(void* const* d_in, const int* in_sizes, int n_in,
                              void* d_out, int out_size, void* d_ws, size_t ws_size,
                              hipStream_t stream) {
    const float* x  = (const float*)d_in[0];
    const float* qw = (const float*)d_in[1];
    const float* kw = (const float*)d_in[2];
    const float* vw = (const float*)d_in[3];
    float* out = (float*)d_out;
    char* ws = (char*)d_ws;
    if (ws_size < 67633152u) return;

    bf16_t* xb = (bf16_t*)(ws + XB_OFF);
    bf16_t* wT = (bf16_t*)(ws + WT_OFF);
    bf16_t* Qb = (bf16_t*)(ws + Q_OFF);
    bf16_t* Kb = (bf16_t*)(ws + K_OFF);
    bf16_t* Vt = (bf16_t*)(ws + VT_OFF);

    cast_kernel<<<8448, 256, 0, stream>>>((const float4*)x, (bf16x4*)xb, qw, kw, vw, wT);
    proj_kernel<<<768, 256, 0, stream>>>(xb, wT, Qb, Kb, Vt);
    attn_kernel<<<512, 512, 0, stream>>>(Qb, Kb, Vt, out);
}

// Round 21
// 102.638 us; speedup vs baseline: 1.0660x; 1.0660x over previous
//
#include <hip/hip_runtime.h>

typedef __bf16 bf16_t;
typedef __attribute__((ext_vector_type(2))) __bf16 bf16x2;
typedef __attribute__((ext_vector_type(4))) __bf16 bf16x4;
typedef __attribute__((ext_vector_type(8))) __bf16 bf16x8;
typedef __attribute__((ext_vector_type(4))) float f32x4;
typedef __attribute__((ext_vector_type(16))) float f32x16;

#define MFMA16(a, b, c) __builtin_amdgcn_mfma_f32_16x16x32_bf16((a), (b), (c), 0, 0, 0)
#define MFMA32(a, b, c) __builtin_amdgcn_mfma_f32_32x32x16_bf16((a), (b), (c), 0, 0, 0)
#define AS1 __attribute__((address_space(1)))
#define AS3 __attribute__((address_space(3)))

// Problem: B=8 S=1024 D=768 H=16 Dh=64 OD=1024, M = B*S = 8192
static constexpr unsigned XB_OFF = 0u;                          // x bf16 row-major: 12,582,912
static constexpr unsigned WT_OFF = 12582912u;                   // wT bf16 (3,1024,768): 4,718,592
static constexpr unsigned Q_OFF  = WT_OFF + 4718592u;           // Qf bf16: 16,777,216
static constexpr unsigned K_OFF  = Q_OFF + 16777216u;
static constexpr unsigned VT_OFF = K_OFF + 16777216u;           // end = 67,633,152

// ---------------- merged cast kernel (unchanged) ----------------
__global__ __launch_bounds__(256) void cast_kernel(const float4* __restrict__ x4,
                                                   bf16x4* __restrict__ out4,
                                                   const float* __restrict__ qw,
                                                   const float* __restrict__ kw,
                                                   const float* __restrict__ vw,
                                                   bf16_t* __restrict__ wT) {
    if (blockIdx.x < 6144u) {
        unsigned i = blockIdx.x * 256u + threadIdx.x;
        float4 v = x4[i];
        bf16x4 o;
        o[0] = (bf16_t)v.x; o[1] = (bf16_t)v.y; o[2] = (bf16_t)v.z; o[3] = (bf16_t)v.w;
        out4[i] = o;
    } else {
        unsigned t = (blockIdx.x - 6144u) * 256u + threadIdx.x;
        unsigned w  = t / 196608u;
        unsigned r  = t % 196608u;
        unsigned n  = r % 1024u;
        unsigned k4 = r / 1024u;
        const float* src = (w == 0u) ? qw : (w == 1u) ? kw : vw;
        float s = (w == 0u) ? 0.18033688011112043f : 1.0f;   // 0.125*log2(e) folded for exp2
        bf16x4 o;
#pragma unroll
        for (int i = 0; i < 4; ++i) o[i] = (bf16_t)(src[(k4 * 4u + i) * 1024u + n] * s);
        *(bf16x4*)&wT[(w * 1024u + n) * 768u + k4 * 4u] = o;
    }
}

// ---------------- fused QKV projection GEMM (r19 exact — best measured) ------
// 3 slots, 72KB, 2 blocks/CU, single-barrier consumption-ordered phases,
// coalesced LDS-transpose epilogue.
__global__ __launch_bounds__(256, 2) void proj_kernel(const bf16_t* __restrict__ xb,
                                                      const bf16_t* __restrict__ wT,
                                                      bf16_t* __restrict__ q,
                                                      bf16_t* __restrict__ k,
                                                      bf16_t* __restrict__ vt) {
    __shared__ __align__(16) char smem[73728];          // 72KB: As 48KB | Bs 24KB
    bf16_t* Asp = (bf16_t*)smem;                        // 3 slots x 8192 elems
    bf16_t* Bsp = (bf16_t*)(smem + 49152);              // 3 slots x 4096 elems
    const int id = blockIdx.x;
    const int work = (id & 7) * 96 + (id >> 3);         // bijective, 768 = 8*96
    const int nb = work & 7, mb = (work >> 3) & 31, wsel = work >> 8;
    const int t = threadIdx.x;
    const int w = t >> 6, l = t & 63;
    const int lo = l & 15, hi = l >> 4;
    const int wm = w >> 1, wn = w & 1;                  // 2x2 waves; per-wave 128x64
    const bf16_t* abase = xb + mb * 256 * 768;
    const bf16_t* bbase = wT + wsel * (1024 * 768) + nb * 128 * 768;
    const int srow = w * 16 + (l >> 2);
    const int gsrc = ((l & 3) ^ ((l >> 3) & 3)) * 8;
    const int rg = (hi ^ ((lo >> 1) & 3)) << 3;         // read-side granule

#define STAGE(slot, p)                                                              \
    do {                                                                            \
        const int ko_ = (p) * 32 + gsrc;                                            \
        _Pragma("unroll")                                                           \
        for (int g_ = 0; g_ < 4; ++g_)                                              \
            __builtin_amdgcn_global_load_lds(                                       \
                (const AS1 void*)(abase + (g_ * 64 + srow) * 768 + ko_),            \
                (AS3 void*)(Asp + (slot) * 8192 + g_ * 2048 + w * 512), 16, 0, 0);  \
        _Pragma("unroll")                                                           \
        for (int g_ = 0; g_ < 2; ++g_)                                              \
            __builtin_amdgcn_global_load_lds(                                       \
                (const AS1 void*)(bbase + (g_ * 64 + srow) * 768 + ko_),            \
                (AS3 void*)(Bsp + (slot) * 4096 + g_ * 2048 + w * 512), 16, 0, 0);  \
    } while (0)

    bf16x8 af[8], bfr[4];
#define DSREAD(slotv)                                                             \
    do {                                                                          \
        const bf16_t* Ab_ = Asp + (slotv) * 8192;                                 \
        const bf16_t* Bb_ = Bsp + (slotv) * 4096;                                 \
        _Pragma("unroll") for (int m_ = 0; m_ < 8; ++m_)                          \
            af[m_] = *(const bf16x8*)&Ab_[(wm * 128 + m_ * 16 + lo) * 32 + rg];   \
        _Pragma("unroll") for (int n_ = 0; n_ < 4; ++n_)                          \
            bfr[n_] = *(const bf16x8*)&Bb_[(wn * 64 + n_ * 16 + lo) * 32 + rg];   \
    } while (0)

#define DOMFMA()                                                                  \
    do {                                                                          \
        __builtin_amdgcn_s_setprio(1);                                            \
        _Pragma("unroll") for (int m_ = 0; m_ < 8; ++m_)                          \
        _Pragma("unroll") for (int n_ = 0; n_ < 4; ++n_)                          \
            acc[m_][n_] = MFMA16(af[m_], bfr[n_], acc[m_][n_]);                   \
        __builtin_amdgcn_s_setprio(0);                                            \
    } while (0)

    f32x4 acc[8][4];
#pragma unroll
    for (int m = 0; m < 8; ++m)
#pragma unroll
        for (int n = 0; n < 4; ++n)
#pragma unroll
            for (int i = 0; i < 4; ++i) acc[m][n][i] = 0.f;

    STAGE(0, 0);
    STAGE(1, 1);
    asm volatile("s_waitcnt vmcnt(6)" ::: "memory");
    __builtin_amdgcn_s_barrier();

    int slot = 0;
    for (int p = 0; p < 22; ++p) {
        DSREAD(slot);                                      // slot p published
        const int s2 = (slot + 2 >= 3) ? slot - 1 : slot + 2;
        STAGE(s2, p + 2);                                  // slot p-1: reads consumed at p-1
        DOMFMA();                                          // consumes DSREAD(p)
        asm volatile("s_waitcnt vmcnt(6)" ::: "memory");   // stage(p+1) landed
        __builtin_amdgcn_s_barrier();                      // publish slot p+1
        slot = (slot + 1 >= 3) ? 0 : slot + 1;
    }
    // tail: p = 22, 23
    DSREAD(1);
    DOMFMA();
    asm volatile("s_waitcnt vmcnt(0)" ::: "memory");       // stage(23) landed
    __builtin_amdgcn_s_barrier();
    DSREAD(2);
    DOMFMA();
#undef STAGE
#undef DSREAD
#undef DOMFMA

    // ---- epilogue: LDS transpose -> 16 coalesced 1KB chunk stores per wave ----
    asm volatile("s_waitcnt lgkmcnt(0)" ::: "memory");
    __builtin_amdgcn_s_barrier();            // all waves past final DSREAD; LDS free
    bf16_t* ep = (bf16_t*)(smem + (unsigned)w * 16384u);   // per-wave 16KB carve
    if (wsel != 2) {
        const int lA = ((lo >> 3) & 1) * 32 + hi * 4;
#pragma unroll
        for (int m = 0; m < 8; ++m)
#pragma unroll
            for (int n = 0; n < 4; ++n)
#pragma unroll
                for (int r = 0; r < 4; ++r)
                    ep[((m >> 1) * 4 + n) * 512 + (lA + (m & 1) * 16 + r) * 8 + (lo & 7)] =
                        (bf16_t)acc[m][n][r];
    } else {
#pragma unroll
        for (int m = 0; m < 8; ++m)
#pragma unroll
            for (int n = 0; n < 4; ++n)
#pragma unroll
                for (int r = 0; r < 4; ++r) {
                    const int sr = hi * 4 + r;   // ss&15
                    ep[((m >> 2) * 8 + (m & 3) * 2 + (n >> 1)) * 512
                       + (((sr >> 3) & 1) * 32 + (n & 1) * 16 + lo) * 8 + (sr & 7)] =
                        (bf16_t)acc[m][n][r];
                }
    }
    asm volatile("s_waitcnt lgkmcnt(0)" ::: "memory");
    __builtin_amdgcn_sched_barrier(0);       // rule #18: pin reads after the wait
    const unsigned headoff = (unsigned)((mb >> 2) * 16 + nb * 2 + wn) << 16;
    bf16_t* dst = (wsel == 0) ? q : (wsel == 1) ? k : vt;
#pragma unroll
    for (int c = 0; c < 16; ++c) {
        unsigned gchunk;
        if (wsel == 0) {
            const int m2 = c >> 2, sq = c & 3;
            gchunk = (unsigned)(((mb & 3) * 8 + wm * 4 + m2) * 4 + sq);
        } else if (wsel == 1) {
            const int m2 = c >> 2, sq = c & 3;
            gchunk = (unsigned)(((mb & 3) * 4 + wm * 2 + (m2 >> 1)) * 8 + sq * 2 + (m2 & 1));
        } else {
            const int ktl = c >> 3, S = (c >> 1) & 3, hl = c & 1;
            gchunk = (unsigned)(((mb & 3) * 4 + wm * 2 + ktl) * 8 + S * 2 + hl);
        }
        *(bf16x8*)&dst[headoff + gchunk * 512u + l * 8] = *(const bf16x8*)&ep[c * 512 + l * 8];
    }
}

// ---------------- flash attention (r18 exact — best measured, 48.4us) --------
// 8 waves share staged K/V; 2 pair-slots (2 kt tiles each), LDS 64KB
// (2 blocks/CU, olds aliased). 2-tile ILP phase order + deferred lsum.
__global__ __launch_bounds__(512) void attn_kernel(const bf16_t* __restrict__ Q,
                                                   const bf16_t* __restrict__ K,
                                                   const bf16_t* __restrict__ Vt,
                                                   float* __restrict__ out) {
    __shared__ __align__(16) char asmem[65536];    // kv[2][2 tiles x 8192]; reused as olds
    bf16_t* kvp = (bf16_t*)asmem;
    const int w = threadIdx.x >> 6, l = threadIdx.x & 63;   // w: 0..7
    const int hb = blockIdx.x & 127;             // head: fixes XCD by hb%8
    const int qblk = blockIdx.x >> 7;            // 0..3
    const int qw = qblk * 8 + w;                 // q-tile 0..31 within head
    const int b = hb >> 4, h = hb & 15;
    const int ln = l & 31, hi = l >> 5;
    const unsigned bh = (unsigned)hb << 16;
    const bf16_t* Qh = Q + bh;
    const bf16_t* Kh = K + bh;
    const bf16_t* Vh = Vt + bh;
    const int l8 = l * 8;

#define ASTAGE2(slot, pair)                                                      \
    do {                                                                         \
        _Pragma("unroll")                                                        \
        for (int tt = 0; tt < 2; ++tt) {                                         \
            const bf16_t* ks_ = Kh + ((pair) * 2 + tt) * 4096;                   \
            const bf16_t* vs_ = Vh + ((pair) * 2 + tt) * 4096;                   \
            bf16_t* dst_ = kvp + (slot) * 16384 + tt * 8192;                     \
            __builtin_amdgcn_global_load_lds(                                    \
                (const AS1 void*)(ks_ + w * 512 + l8),                           \
                (AS3 void*)(dst_ + w * 512), 16, 0, 0);                          \
            __builtin_amdgcn_global_load_lds(                                    \
                (const AS1 void*)(vs_ + w * 512 + l8),                           \
                (AS3 void*)(dst_ + 4096 + w * 512), 16, 0, 0);                   \
        }                                                                        \
    } while (0)

    bf16x8 qf[4];
#pragma unroll
    for (int s = 0; s < 4; ++s)
        qf[s] = *(const bf16x8*)&Qh[(qw * 4 + s) * 512 + l8];

    f32x16 of0, of1;
#pragma unroll
    for (int r = 0; r < 16; ++r) { of0[r] = 0.f; of1[r] = 0.f; }
    float sacc[16];
#pragma unroll
    for (int r = 0; r < 16; ++r) sacc[r] = 0.f;

#define ATILE_QK(Kt, sc0, sc1)                                                   \
    do {                                                                         \
        _Pragma("unroll") for (int r = 0; r < 16; ++r) { sc0[r] = 0.f; sc1[r] = 0.f; } \
        __builtin_amdgcn_s_setprio(1);                                           \
        _Pragma("unroll") for (int s = 0; s < 4; ++s) {                          \
            bf16x8 k0 = *(const bf16x8*)&(Kt)[(s * 2 + 0) * 512 + l8];           \
            bf16x8 k1 = *(const bf16x8*)&(Kt)[(s * 2 + 1) * 512 + l8];           \
            sc0 = MFMA32(k0, qf[s], sc0);                                        \
            sc1 = MFMA32(k1, qf[s], sc1);                                        \
        }                                                                        \
        __builtin_amdgcn_s_setprio(0);                                           \
    } while (0)

#define ATILE_SM(sc0, sc1, own)                                                  \
    do {                                                                         \
        float p0[16], p1[16];                                                    \
        _Pragma("unroll") for (int r = 0; r < 16; ++r) {                         \
            p0[r] = __builtin_amdgcn_exp2f(sc0[r]);                              \
            p1[r] = __builtin_amdgcn_exp2f(sc1[r]);                              \
        }                                                                        \
        _Pragma("unroll") for (int r = 0; r < 16; ++r) sacc[r] += p0[r] + p1[r]; \
        _Pragma("unroll") for (int t2 = 0; t2 < 8; ++t2) {                       \
            bf16x2 v0; v0[0] = (bf16_t)p0[2 * t2]; v0[1] = (bf16_t)p0[2 * t2 + 1]; \
            bf16x2 v1; v1[0] = (bf16_t)p1[2 * t2]; v1[1] = (bf16_t)p1[2 * t2 + 1]; \
            own[t2]     = __builtin_bit_cast(unsigned, v0);                      \
            own[8 + t2] = __builtin_bit_cast(unsigned, v1);                      \
        }                                                                        \
    } while (0)

#define ATILE_PV(Vtt, own)                                                       \
    do {                                                                         \
        bf16x8 vf0[4], vf1[4];                                                   \
        _Pragma("unroll") for (int S = 0; S < 4; ++S) {                          \
            vf0[S] = *(const bf16x8*)&(Vtt)[(S * 2 + 0) * 512 + l8];             \
            vf1[S] = *(const bf16x8*)&(Vtt)[(S * 2 + 1) * 512 + l8];             \
        }                                                                        \
        __builtin_amdgcn_s_setprio(1);                                           \
        _Pragma("unroll") for (int S = 0; S < 4; ++S) {                          \
            const int b0 = (S >> 1) * 8 + (S & 1) * 4;                           \
            unsigned w0 = own[b0 + 0], w2 = own[b0 + 2];                         \
            unsigned w1 = own[b0 + 1], w3 = own[b0 + 3];                         \
            asm("v_permlane32_swap_b32 %0, %1" : "+v"(w0), "+v"(w2));            \
            asm("v_permlane32_swap_b32 %0, %1" : "+v"(w1), "+v"(w3));            \
            union { unsigned u[4]; bf16x8 v; } pb;                               \
            pb.u[0] = w0; pb.u[1] = w1; pb.u[2] = w2; pb.u[3] = w3;              \
            of0 = MFMA32(vf0[S], pb.v, of0);                                     \
            of1 = MFMA32(vf1[S], pb.v, of1);                                     \
        }                                                                        \
        __builtin_amdgcn_s_setprio(0);                                           \
    } while (0)

#define ACOMPUTE2(cur)                                                           \
    do {                                                                         \
        const bf16_t* KtA = kvp + (cur) * 16384;                                 \
        const bf16_t* VtA = KtA + 4096;                                          \
        const bf16_t* KtB = KtA + 8192;                                          \
        const bf16_t* VtB = KtA + 12288;                                         \
        f32x16 scA0, scA1;                                                       \
        ATILE_QK(KtA, scA0, scA1);                                               \
        unsigned ownA[16];                                                       \
        ATILE_SM(scA0, scA1, ownA);                                              \
        f32x16 scB0, scB1;                                                       \
        ATILE_QK(KtB, scB0, scB1);                                               \
        ATILE_PV(VtA, ownA);                                                     \
        unsigned ownB[16];                                                       \
        ATILE_SM(scB0, scB1, ownB);                                              \
        ATILE_PV(VtB, ownB);                                                     \
    } while (0)

    // prologue: both slots staged (pairs 0,1), publish slot 0
    ASTAGE2(0, 0);
    ASTAGE2(1, 1);
    asm volatile("s_waitcnt vmcnt(4)" ::: "memory");
    __builtin_amdgcn_s_barrier();

    for (int p = 0; p < 6; ++p) {
        const int cur = p & 1;
        ACOMPUTE2(cur);
        asm volatile("s_waitcnt lgkmcnt(0)" ::: "memory");  // my reads of slot cur done
        __builtin_amdgcn_s_barrier();                        // all waves done: cur free
        ASTAGE2(cur, p + 2);                                 // refill cur for pair p+2
        asm volatile("s_waitcnt vmcnt(4)" ::: "memory");     // stage(p+1) landed
        __builtin_amdgcn_s_barrier();                        // publish slot cur^1
    }
    // tail: pairs 6, 7
    ACOMPUTE2(0);
    asm volatile("s_waitcnt lgkmcnt(0)" ::: "memory");
    __builtin_amdgcn_s_barrier();
    asm volatile("s_waitcnt vmcnt(0)" ::: "memory");         // stage(7) landed
    __builtin_amdgcn_s_barrier();
    ACOMPUTE2(1);
#undef ASTAGE2
#undef ACOMPUTE2
#undef ATILE_QK
#undef ATILE_SM
#undef ATILE_PV

    // ---- all kv reads retired before olds overwrites the staging space ----
    asm volatile("s_waitcnt lgkmcnt(0)" ::: "memory");
    __builtin_amdgcn_s_barrier();

    // epilogue: deferred lsum tree + normalize + XOR-swizzled transpose + store
#pragma unroll
    for (int st = 8; st >= 1; st >>= 1)
#pragma unroll
        for (int r = 0; r < 8; ++r)
            if (r < st) sacc[r] += sacc[r + st];
    float ltot = sacc[0] + __shfl_xor(sacc[0], 32);
    float inv = 1.f / ltot;
    float* ol = (float*)asmem + (unsigned)w * 2048u;   // per-wave 8KB carve (8x8KB=64KB)
#pragma unroll
    for (int r = 0; r < 16; ++r) {
        int d = (r & 3) + 8 * (r >> 2) + 4 * hi;
        int d2 = 32 + d;
        ol[d * 32 + (ln ^ (d & 31))]    = of0[r] * inv;
        ol[d2 * 32 + (ln ^ (d2 & 31))]  = of1[r] * inv;
    }
    const unsigned obase = (unsigned)(b * 1024 + qw * 32) * 1024u + h * 64 + l;
#pragma unroll 8
    for (int qq = 0; qq < 32; ++qq)
        out[obase + qq * 1024u] = ol[l * 32 + (qq ^ (l & 31))];
}

extern "C" void kernel_launch(void* const* d_in, const int* in_sizes, int n_in,
                              void* d_out, int out_size, void* d_ws, size_t ws_size,
                              hipStream_t stream) {
    const float* x  = (const float*)d_in[0];
    const float* qw = (const float*)d_in[1];
    const float* kw = (const float*)d_in[2];
    const float* vw = (const float*)d_in[3];
    float* out = (float*)d_out;
    char* ws = (char*)d_ws;
    if (ws_size < 67633152u) return;

    bf16_t* xb = (bf16_t*)(ws + XB_OFF);
    bf16_t* wT = (bf16_t*)(ws + WT_OFF);
    bf16_t* Qb = (bf16_t*)(ws + Q_OFF);
    bf16_t* Kb = (bf16_t*)(ws + K_OFF);
    bf16_t* Vt = (bf16_t*)(ws + VT_OFF);

    cast_kernel<<<8448, 256, 0, stream>>>((const float4*)x, (bf16x4*)xb, qw, kw, vw, wT);
    proj_kernel<<<768, 256, 0, stream>>>(xb, wT, Qb, Kb, Vt);
    attn_kernel<<<512, 512, 0, stream>>>(Qb, Kb, Vt, out);
}